// Round 11
// baseline (200.116 us; speedup 1.0000x reference)
//
#include <hip/hip_runtime.h>
#include <math.h>

#ifndef INFINITY
#define INFINITY __builtin_huge_valf()
#endif

static inline int cdiv(int a, int b){ return (a + b - 1) / b; }

typedef __attribute__((ext_vector_type(8))) short bf16x8;
typedef __attribute__((ext_vector_type(4))) float f32x4;

static __device__ __forceinline__ short f2bf(float f){
  unsigned u = __float_as_uint(f);
  unsigned r = (u + 0x7fffu + ((u >> 16) & 1u)) >> 16;
  return (short)r;
}
static __device__ __forceinline__ unsigned pk2bf(float lo, float hi){
  return ((unsigned)(unsigned short)f2bf(hi) << 16) | (unsigned short)(unsigned)f2bf(lo);
}
static __device__ __forceinline__ float bflo(unsigned pair){
  return __uint_as_float((pair & 0xffffu) << 16);
}
static __device__ __forceinline__ float bfhi(unsigned pair){
  return __uint_as_float(pair & 0xffff0000u);
}

// ---------------- utility ----------------

__global__ void zero_i32_k(int* __restrict__ p, int n){
  int i = blockIdx.x * blockDim.x + threadIdx.x;
  if (i < n) p[i] = 0;
}

// fused weight prep: 4 transposes (blocks 0..511) + 4 combined attention vectors (blocks 512..514)
__global__ __launch_bounds__(256) void prepc_k(
    const float* __restrict__ Ws1, short* __restrict__ T1,
    const float* __restrict__ Wl1, short* __restrict__ T2,
    const float* __restrict__ Ws2, short* __restrict__ T3,
    const float* __restrict__ Wl2, short* __restrict__ T4,
    const float* __restrict__ as1, const float* __restrict__ Wd1, const float* __restrict__ ad1,
    const float* __restrict__ as2, const float* __restrict__ Wd2, const float* __restrict__ ad2,
    float* __restrict__ wa_s1, float* __restrict__ wa_d1,
    float* __restrict__ wa_s2, float* __restrict__ wa_d2){
  int g = blockIdx.x;
  if (g < 512){
    const float* W; short* T; int K; int c;
    if (g < 128){ W = Ws1; T = T1; K = 256; c = g; }
    else if (g < 256){ W = Wl1; T = T2; K = 256; c = g - 128; }
    else if (g < 384){ W = Ws2; T = T3; K = 128; c = g - 256; }
    else { W = Wl2; T = T4; K = 128; c = g - 384; }
    for (int k = threadIdx.x; k < K; k += blockDim.x)
      T[(size_t)c * K + k] = f2bf(W[(size_t)k * 128 + c]);
  } else {
    int t = (g - 512) * 256 + threadIdx.x;
    const float* row; const float* a; float* out; int idx;
    if (t < 256){ row = Ws1 + (size_t)t * 128;          a = as1; out = wa_s1; idx = t; }
    else if (t < 512){ row = Wd1 + (size_t)(t-256)*128; a = ad1; out = wa_d1; idx = t-256; }
    else if (t < 640){ row = Ws2 + (size_t)(t-512)*128; a = as2; out = wa_s2; idx = t-512; }
    else { row = Wd2 + (size_t)(t-640)*128;             a = ad2; out = wa_d2; idx = t-640; }
    float s = 0.f;
    #pragma unroll 8
    for (int j = 0; j < 128; ++j) s += row[j] * a[j];
    out[idx] = s;
  }
}

// ---------------- CSR build ----------------

__global__ void deg_count_k(const int* __restrict__ dst, int E, int* __restrict__ deg){
  int e = blockIdx.x * blockDim.x + threadIdx.x;
  if (e < E) atomicAdd(&deg[dst[e]], 1);
}

__global__ __launch_bounds__(1024) void scan1_k(const int* __restrict__ deg, int N,
    int* __restrict__ rowptr, int* __restrict__ bsum){
  __shared__ int buf[1024];
  int t = threadIdx.x;
  int i = blockIdx.x * 1024 + t;
  int v = (i < N) ? deg[i] : 0;
  buf[t] = v;
  __syncthreads();
  #pragma unroll
  for (int o = 1; o < 1024; o <<= 1){
    int add = (t >= o) ? buf[t - o] : 0;
    __syncthreads();
    buf[t] += add;
    __syncthreads();
  }
  if (i < N) rowptr[i] = buf[t] - v;
  if (t == 1023) bsum[blockIdx.x] = buf[1023];
}

__global__ __launch_bounds__(1024) void scan2_k(int* __restrict__ bsum, int nb,
    int* __restrict__ total_out){
  __shared__ int buf[1024];
  int t = threadIdx.x;
  int v = (t < nb) ? bsum[t] : 0;
  buf[t] = v;
  __syncthreads();
  #pragma unroll
  for (int o = 1; o < 1024; o <<= 1){
    int add = (t >= o) ? buf[t - o] : 0;
    __syncthreads();
    buf[t] += add;
    __syncthreads();
  }
  if (t < nb) bsum[t] = buf[t] - v;
  if (t == 1023) *total_out = buf[1023];
}

__global__ __launch_bounds__(1024) void scan3_k(int* __restrict__ rowptr, int* __restrict__ cursor,
    const int* __restrict__ boff, int N){
  int i = blockIdx.x * 1024 + threadIdx.x;
  if (i < N){
    int r = rowptr[i] + boff[blockIdx.x];
    rowptr[i] = r;
    cursor[i] = r;
  }
}

__global__ void scatter_k(const int* __restrict__ src, const int* __restrict__ dst, int E,
                          int* __restrict__ cursor, int* __restrict__ csrs, int* __restrict__ csrd){
  int e = blockIdx.x * blockDim.x + threadIdx.x;
  if (e < E){
    int d = dst[e];
    int p = atomicAdd(&cursor[d], 1);
    csrs[p] = src[e];
    csrd[p] = d;
  }
}

// per-CSR-slot softmax weight: ew[j] = exp(leaky_relu(als[src]+ald[dst]))
__global__ void ew_k(const int* __restrict__ csrs, const int* __restrict__ csrd,
                     const float* __restrict__ als, const float* __restrict__ ald,
                     float* __restrict__ ew, int E){
  int e = blockIdx.x * blockDim.x + threadIdx.x;
  if (e < E){
    float t = als[csrs[e]] + ald[csrd[e]];
    t = (t > 0.f) ? t : 0.2f * t;
    ew[e] = __expf(t);
  }
}

// ---------------- layer-1 GEMM: 64x128 tile, double-buffered LDS, 1 barrier/K-step ----------------
// fp32 A cast during staging, dual bf16 C, fp32 attention dots folded after LDS store.

__global__ __launch_bounds__(256) void gemm1_k(const float* __restrict__ X,
    const short* __restrict__ BT1, const short* __restrict__ BT2,
    const float* __restrict__ vs, const float* __restrict__ vd,
    short* __restrict__ C1, short* __restrict__ C2,
    float* __restrict__ als, float* __restrict__ ald, int M){
  const int K = 256, NS = 8;
  __shared__ int4 As[2][256];
  __shared__ int4 Bs1[2][512];
  __shared__ int4 Bs2[2][512];
  const int tid = threadIdx.x;
  const int lane = tid & 63, wid = tid >> 6;
  const int wm = wid >> 1, wn = wid & 1;
  const int l15 = lane & 15, lhi = lane >> 4;
  const int row0 = blockIdx.x * 64;
  const int r = tid >> 2, slot = tid & 3;
  const int so = (slot * 16) ^ ((r & 3) << 4);
  const float4 z4 = make_float4(0.f, 0.f, 0.f, 0.f);

  const bool av = row0 + r < M;
  const float* A0 = X + (size_t)(row0 + (av ? r : 0)) * K + slot * 8;
  const short* B10 = BT1 + (size_t)r * K + slot * 8;
  const short* B11 = BT1 + (size_t)(r + 64) * K + slot * 8;
  const short* B20 = BT2 + (size_t)r * K + slot * 8;
  const short* B21 = BT2 + (size_t)(r + 64) * K + slot * 8;
  const float* vsp = vs + slot * 8;
  const float* vdp = vd + slot * 8;

  f32x4 acc[2][4], acc2[2][4];
  #pragma unroll
  for (int m = 0; m < 2; ++m)
    #pragma unroll
    for (int n = 0; n < 4; ++n){ acc[m][n] = (f32x4)(0.f); acc2[m][n] = (f32x4)(0.f); }
  float dps = 0.f, dpd = 0.f;

  float4 f0, f1, vl, vh, wl, wh;
  int4 rb10, rb11, rb20, rb21;

#define G1_LOAD(kk) do{ \
    f0 = av ? *(const float4*)(A0 + (kk)) : z4; \
    f1 = av ? *(const float4*)(A0 + (kk) + 4) : z4; \
    rb10 = *(const int4*)(B10 + (kk)); rb11 = *(const int4*)(B11 + (kk)); \
    rb20 = *(const int4*)(B20 + (kk)); rb21 = *(const int4*)(B21 + (kk)); \
    vl = *(const float4*)(vsp + (kk)); vh = *(const float4*)(vsp + (kk) + 4); \
    wl = *(const float4*)(vdp + (kk)); wh = *(const float4*)(vdp + (kk) + 4); \
  }while(0)

#define G1_STORE(buf) do{ \
    int4 avi; \
    avi.x = (int)pk2bf(f0.x, f0.y); avi.y = (int)pk2bf(f0.z, f0.w); \
    avi.z = (int)pk2bf(f1.x, f1.y); avi.w = (int)pk2bf(f1.z, f1.w); \
    *(int4*)((char*)As[buf] + r * 64 + so) = avi; \
    *(int4*)((char*)Bs1[buf] + r * 64 + so)        = rb10; \
    *(int4*)((char*)Bs1[buf] + (r + 64) * 64 + so) = rb11; \
    *(int4*)((char*)Bs2[buf] + r * 64 + so)        = rb20; \
    *(int4*)((char*)Bs2[buf] + (r + 64) * 64 + so) = rb21; \
  }while(0)

#define G1_DOTS() do{ \
    dps += f0.x*vl.x + f0.y*vl.y + f0.z*vl.z + f0.w*vl.w \
         + f1.x*vh.x + f1.y*vh.y + f1.z*vh.z + f1.w*vh.w; \
    dpd += f0.x*wl.x + f0.y*wl.y + f0.z*wl.z + f0.w*wl.w \
         + f1.x*wh.x + f1.y*wh.y + f1.z*wh.z + f1.w*wh.w; \
  }while(0)

  G1_LOAD(0);
  G1_STORE(0);
  G1_DOTS();
  __syncthreads();
  for (int s = 0; s < NS; ++s){
    const int cur = s & 1;
    const bool more = (s + 1 < NS);
    if (more) G1_LOAD((s + 1) * 32);      // in flight across MFMA below
    bf16x8 af[2], b1f[4], b2f[4];
    #pragma unroll
    for (int m = 0; m < 2; ++m){
      int ar = wm * 32 + m * 16 + l15;
      af[m] = *(const bf16x8*)((const char*)As[cur] + ar * 64 + ((lhi * 16) ^ ((ar & 3) << 4)));
    }
    #pragma unroll
    for (int n = 0; n < 4; ++n){
      int bc = wn * 64 + n * 16 + l15;
      int bo = (lhi * 16) ^ ((bc & 3) << 4);
      b1f[n] = *(const bf16x8*)((const char*)Bs1[cur] + bc * 64 + bo);
      b2f[n] = *(const bf16x8*)((const char*)Bs2[cur] + bc * 64 + bo);
    }
    #pragma unroll
    for (int m = 0; m < 2; ++m)
      #pragma unroll
      for (int n = 0; n < 4; ++n){
        acc[m][n]  = __builtin_amdgcn_mfma_f32_16x16x32_bf16(af[m], b1f[n], acc[m][n], 0, 0, 0);
        acc2[m][n] = __builtin_amdgcn_mfma_f32_16x16x32_bf16(af[m], b2f[n], acc2[m][n], 0, 0, 0);
      }
    if (more){
      G1_STORE(cur ^ 1);
      G1_DOTS();
      __syncthreads();
    }
  }
#undef G1_LOAD
#undef G1_STORE
#undef G1_DOTS
  #pragma unroll
  for (int m = 0; m < 2; ++m)
    #pragma unroll
    for (int n = 0; n < 4; ++n){
      int col = wn * 64 + n * 16 + l15;
      #pragma unroll
      for (int rr = 0; rr < 4; ++rr){
        int row = row0 + wm * 32 + m * 16 + lhi * 4 + rr;
        if (row < M){
          C1[(size_t)row * 128 + col] = f2bf(acc[m][n][rr]);
          C2[(size_t)row * 128 + col] = f2bf(acc2[m][n][rr]);
        }
      }
    }
  dps += __shfl_xor(dps, 1); dps += __shfl_xor(dps, 2);
  dpd += __shfl_xor(dpd, 1); dpd += __shfl_xor(dpd, 2);
  if (slot == 0 && av){ als[row0 + r] = dps; ald[row0 + r] = dpd; }
}

// ---------------- layer-2 GEMM: 64x128 tile, double-buffered LDS, dual B, bf16 C ----------------

__global__ __launch_bounds__(256) void gemm2_k(const short* __restrict__ A,
    const short* __restrict__ BT1, const short* __restrict__ BT2,
    short* __restrict__ C1, short* __restrict__ C2, int M){
  const int K = 128, NS = 4;
  __shared__ int4 As[2][256];
  __shared__ int4 Bs1[2][512];
  __shared__ int4 Bs2[2][512];
  const int tid = threadIdx.x;
  const int lane = tid & 63, wid = tid >> 6;
  const int wm = wid >> 1, wn = wid & 1;
  const int l15 = lane & 15, lhi = lane >> 4;
  const int row0 = blockIdx.x * 64;
  const int r = tid >> 2, slot = tid & 3;
  const int so = (slot * 16) ^ ((r & 3) << 4);
  const int4 zi4 = make_int4(0, 0, 0, 0);

  const bool av = row0 + r < M;
  const short* A0 = A + (size_t)(row0 + (av ? r : 0)) * K + slot * 8;
  const short* B10 = BT1 + (size_t)r * K + slot * 8;
  const short* B11 = BT1 + (size_t)(r + 64) * K + slot * 8;
  const short* B20 = BT2 + (size_t)r * K + slot * 8;
  const short* B21 = BT2 + (size_t)(r + 64) * K + slot * 8;

  f32x4 acc[2][4], acc2[2][4];
  #pragma unroll
  for (int m = 0; m < 2; ++m)
    #pragma unroll
    for (int n = 0; n < 4; ++n){ acc[m][n] = (f32x4)(0.f); acc2[m][n] = (f32x4)(0.f); }

  int4 ra, rb10, rb11, rb20, rb21;

#define G2_LOAD(kk) do{ \
    ra = av ? *(const int4*)(A0 + (kk)) : zi4; \
    rb10 = *(const int4*)(B10 + (kk)); rb11 = *(const int4*)(B11 + (kk)); \
    rb20 = *(const int4*)(B20 + (kk)); rb21 = *(const int4*)(B21 + (kk)); \
  }while(0)

#define G2_STORE(buf) do{ \
    *(int4*)((char*)As[buf] + r * 64 + so) = ra; \
    *(int4*)((char*)Bs1[buf] + r * 64 + so)        = rb10; \
    *(int4*)((char*)Bs1[buf] + (r + 64) * 64 + so) = rb11; \
    *(int4*)((char*)Bs2[buf] + r * 64 + so)        = rb20; \
    *(int4*)((char*)Bs2[buf] + (r + 64) * 64 + so) = rb21; \
  }while(0)

  G2_LOAD(0);
  G2_STORE(0);
  __syncthreads();
  for (int s = 0; s < NS; ++s){
    const int cur = s & 1;
    const bool more = (s + 1 < NS);
    if (more) G2_LOAD((s + 1) * 32);
    bf16x8 af[2], b1f[4], b2f[4];
    #pragma unroll
    for (int m = 0; m < 2; ++m){
      int ar = wm * 32 + m * 16 + l15;
      af[m] = *(const bf16x8*)((const char*)As[cur] + ar * 64 + ((lhi * 16) ^ ((ar & 3) << 4)));
    }
    #pragma unroll
    for (int n = 0; n < 4; ++n){
      int bc = wn * 64 + n * 16 + l15;
      int bo = (lhi * 16) ^ ((bc & 3) << 4);
      b1f[n] = *(const bf16x8*)((const char*)Bs1[cur] + bc * 64 + bo);
      b2f[n] = *(const bf16x8*)((const char*)Bs2[cur] + bc * 64 + bo);
    }
    #pragma unroll
    for (int m = 0; m < 2; ++m)
      #pragma unroll
      for (int n = 0; n < 4; ++n){
        acc[m][n]  = __builtin_amdgcn_mfma_f32_16x16x32_bf16(af[m], b1f[n], acc[m][n], 0, 0, 0);
        acc2[m][n] = __builtin_amdgcn_mfma_f32_16x16x32_bf16(af[m], b2f[n], acc2[m][n], 0, 0, 0);
      }
    if (more){
      G2_STORE(cur ^ 1);
      __syncthreads();
    }
  }
#undef G2_LOAD
#undef G2_STORE
  #pragma unroll
  for (int m = 0; m < 2; ++m)
    #pragma unroll
    for (int n = 0; n < 4; ++n){
      int col = wn * 64 + n * 16 + l15;
      #pragma unroll
      for (int rr = 0; rr < 4; ++rr){
        int row = row0 + wm * 32 + m * 16 + lhi * 4 + rr;
        if (row < M){
          C1[(size_t)row * 128 + col] = f2bf(acc[m][n][rr]);
          C2[(size_t)row * 128 + col] = f2bf(acc2[m][n][rr]);
        }
      }
    }
}

// ---------------- layer-1 aggregation: precomputed edge weights, uniform loads, no shfl ----------------

__global__ __launch_bounds__(256) void agg1_k(const int* __restrict__ rowptr, const int* __restrict__ csrs,
    const float* __restrict__ ew,
    const short* __restrict__ hsrcb,
    const short* __restrict__ linb, const float* __restrict__ bg, const float* __restrict__ bl,
    const float* __restrict__ ws2, const float* __restrict__ wd2,
    short* __restrict__ outb, float* __restrict__ als2, float* __restrict__ ald2, int N){
  int w = (blockIdx.x * blockDim.x + threadIdx.x) >> 6;
  int lane = threadIdx.x & 63;
  if (w >= N) return;
  int beg = rowptr[w], end = rowptr[w + 1];
  float den = 0.f, a0 = 0.f, a1 = 0.f;
  int ch = lane << 1;
  for (int j0 = beg; j0 < end; j0 += 8){
    int sq[8]; float wq[8]; unsigned hp[8];
    #pragma unroll
    for (int u = 0; u < 8; ++u){
      int j = j0 + u;
      bool act = j < end;
      sq[u] = csrs[act ? j : beg];
      wq[u] = act ? ew[j] : 0.f;
    }
    #pragma unroll
    for (int u = 0; u < 8; ++u)
      hp[u] = *(const unsigned*)(hsrcb + (size_t)sq[u] * 128 + ch);
    #pragma unroll
    for (int u = 0; u < 8; ++u){
      den += wq[u];
      a0 += wq[u] * bflo(hp[u]); a1 += wq[u] * bfhi(hp[u]);
    }
  }
  float inv = (end > beg) ? 1.f / den : 0.f;
  unsigned lp = *(const unsigned*)(linb + (size_t)w * 128 + ch);
  float o0 = a0 * inv + bg[ch]     + bl[ch]     + bflo(lp);
  float o1 = a1 * inv + bg[ch + 1] + bl[ch + 1] + bfhi(lp);
  o0 = fmaxf(o0, 0.f); o1 = fmaxf(o1, 0.f);
  *(unsigned*)(outb + (size_t)w * 128 + ch) = pk2bf(o0, o1);
  float s2 = o0 * ws2[ch] + o1 * ws2[ch + 1];
  float d2 = o0 * wd2[ch] + o1 * wd2[ch + 1];
  #pragma unroll
  for (int o = 32; o; o >>= 1){ s2 += __shfl_xor(s2, o); d2 += __shfl_xor(d2, o); }
  if (lane == 0){ als2[w] = s2; ald2[w] = d2; }
}

// ---------------- fused tail: proj (fc3) + layer-2 aggregation (8 persons/block) + head ----------------

__global__ __launch_bounds__(512) void tail_k(
    const float* __restrict__ xp, const int* __restrict__ prjidx,
    const float* __restrict__ W3, const float* __restrict__ b3,
    const int* __restrict__ pidx,
    const int* __restrict__ rowptr, const int* __restrict__ csrs, const float* __restrict__ ew,
    const short* __restrict__ h2,
    const short* __restrict__ lin2all,
    const float* __restrict__ bg, const float* __restrict__ bl,
    const float* __restrict__ Wf1, const float* __restrict__ bf1,
    const float* __restrict__ Wf2, const float* __restrict__ bf2,
    float* __restrict__ outp, int Dp){
  __shared__ float xs[768];
  __shared__ float part[4][128];
  __shared__ float pe[8][128];
  __shared__ float pr[128];
  int b = blockIdx.x, t = threadIdx.x;
  // proj staging
  const float* xr = xp + (size_t)prjidx[b] * Dp;
  for (int i = t; i < Dp / 4; i += 512)
    ((float4*)xs)[i] = ((const float4*)xr)[i];
  __syncthreads();
  { int c = t & 127, h = t >> 7;
    float acc = 0.f;
    #pragma unroll 8
    for (int k = 0; k < 192; ++k)
      acc = fmaf(xs[h * 192 + k], W3[(size_t)(h * 192 + k) * 128 + c], acc);
    part[h][c] = acc; }
  // agg2: wave wv handles person b*8+wv
  int wv = t >> 6, lane = t & 63;
  int p = b * 8 + wv;
  int nd = pidx[p];
  int ch = lane << 1;
  int beg = rowptr[nd], end = rowptr[nd + 1];
  float den = 0.f, a0 = 0.f, a1 = 0.f;
  for (int j0 = beg; j0 < end; j0 += 8){
    int sq[8]; float wq[8]; unsigned hp[8];
    #pragma unroll
    for (int u = 0; u < 8; ++u){
      int j = j0 + u;
      bool act = j < end;
      sq[u] = csrs[act ? j : beg];
      wq[u] = act ? ew[j] : 0.f;
    }
    #pragma unroll
    for (int u = 0; u < 8; ++u)
      hp[u] = *(const unsigned*)(h2 + (size_t)sq[u] * 128 + ch);
    #pragma unroll
    for (int u = 0; u < 8; ++u){
      den += wq[u];
      a0 += wq[u] * bflo(hp[u]); a1 += wq[u] * bfhi(hp[u]);
    }
  }
  float inv = (end > beg) ? 1.f / den : 0.f;
  unsigned lp = *(const unsigned*)(lin2all + (size_t)nd * 128 + ch);
  pe[wv][ch]     = a0 * inv + bg[ch]     + bl[ch]     + bflo(lp);
  pe[wv][ch + 1] = a1 * inv + bg[ch + 1] + bl[ch + 1] + bfhi(lp);
  __syncthreads();
  if (t < 128) pr[t] = part[0][t] + part[1][t] + part[2][t] + part[3][t] + b3[t];
  __syncthreads();
  // head: wave wv -> person wv; lane covers cols lane, lane+64
  float v = 0.f;
  for (int cc = lane; cc < 128; cc += 64){
    float acc = bf1[cc];
    for (int k = 0; k < 128; ++k)
      acc += pe[wv][k] * Wf1[(size_t)k * 128 + cc] + pr[k] * Wf1[(size_t)(128 + k) * 128 + cc];
    v += fmaxf(acc, 0.f) * Wf2[cc];
  }
  #pragma unroll
  for (int o = 32; o; o >>= 1) v += __shfl_xor(v, o);
  if (lane == 0) outp[(size_t)b * 8 + wv] = v + bf2[0];
}

// ---------------- launch ----------------

extern "C" void kernel_launch(void* const* d_in, const int* in_sizes, int n_in,
                              void* d_out, int out_size, void* d_ws, size_t ws_size,
                              hipStream_t stream){
  const float* x      = (const float*)d_in[0];
  const int*   eidx   = (const int*)d_in[1];
  const float* xproj  = (const float*)d_in[2];
  const int*   pidx   = (const int*)d_in[3];
  const int*   prjidx = (const int*)d_in[4];
  const float* Wsrc1  = (const float*)d_in[5];
  const float* Wdst1  = (const float*)d_in[6];
  const float* asrc1  = (const float*)d_in[7];
  const float* adst1  = (const float*)d_in[8];
  const float* b1     = (const float*)d_in[9];
  const float* Wl1    = (const float*)d_in[10];
  const float* bl1    = (const float*)d_in[11];
  const float* Wsrc2  = (const float*)d_in[12];
  const float* Wdst2  = (const float*)d_in[13];
  const float* asrc2  = (const float*)d_in[14];
  const float* adst2  = (const float*)d_in[15];
  const float* b2     = (const float*)d_in[16];
  const float* Wl2    = (const float*)d_in[17];
  const float* bl2    = (const float*)d_in[18];
  const float* W3     = (const float*)d_in[19];
  const float* b3     = (const float*)d_in[20];
  const float* Wf1    = (const float*)d_in[21];
  const float* bf1    = (const float*)d_in[22];
  const float* Wf2    = (const float*)d_in[23];
  const float* bf2    = (const float*)d_in[24];

  const int DIN = 256, H = 128, DPROJ = 768;
  const int N  = in_sizes[0] / DIN;
  const int E  = in_sizes[1] / 2;
  const int P  = in_sizes[3];            // B*K = 2048
  const int B  = in_sizes[4];            // 256
  const int* srcv = eidx;
  const int* dstv = eidx + E;
  const int NB = cdiv(N, 1024);
  (void)H; (void)P;

  char* ws = (char*)d_ws;
  size_t off = 0;
  auto alloc = [&](size_t bytes) -> void* {
    void* p = ws + off;
    off = (off + bytes + 255) & ~(size_t)255;
    return p;
  };
  short* hbuf   = (short*)alloc((size_t)N * 128 * 2);   // bf16 h_src1, later h_src2
  short* linb   = (short*)alloc((size_t)N * 128 * 2);   // bf16 x@Wl1, later x1@Wl2
  short* x1b    = (short*)alloc((size_t)N * 128 * 2);   // bf16 x1
  float* als1   = (float*)alloc((size_t)N * 4);
  float* ald1   = (float*)alloc((size_t)N * 4);
  float* als2   = (float*)alloc((size_t)N * 4);
  float* ald2   = (float*)alloc((size_t)N * 4);
  float* wa_s1  = (float*)alloc(256 * 4);
  float* wa_d1  = (float*)alloc(256 * 4);
  float* wa_s2  = (float*)alloc(128 * 4);
  float* wa_d2  = (float*)alloc(128 * 4);
  short* WsT1   = (short*)alloc((size_t)128 * 256 * 2);
  short* WlT1   = (short*)alloc((size_t)128 * 256 * 2);
  short* WsT2   = (short*)alloc((size_t)128 * 128 * 2);
  short* WlT2   = (short*)alloc((size_t)128 * 128 * 2);
  int*   deg    = (int*)alloc((size_t)N * 4);
  int*   rowptr = (int*)alloc((size_t)(N + 1) * 4);
  int*   cursor = (int*)alloc((size_t)N * 4);
  int*   bsum   = (int*)alloc((size_t)1024 * 4);
  int*   csrs   = (int*)alloc((size_t)E * 4);
  int*   csrd   = (int*)alloc((size_t)E * 4);
  float* ew     = (float*)alloc((size_t)E * 4);
  (void)ws_size; (void)n_in; (void)out_size;

  // CSR build
  zero_i32_k<<<cdiv(N, 1024), 1024, 0, stream>>>(deg, N);
  deg_count_k<<<cdiv(E, 256), 256, 0, stream>>>(dstv, E, deg);
  scan1_k<<<NB, 1024, 0, stream>>>(deg, N, rowptr, bsum);
  scan2_k<<<1, 1024, 0, stream>>>(bsum, NB, rowptr + N);
  scan3_k<<<NB, 1024, 0, stream>>>(rowptr, cursor, bsum, N);
  scatter_k<<<cdiv(E, 256), 256, 0, stream>>>(srcv, dstv, E, cursor, csrs, csrd);

  // weight prep (transposes + combined attention vectors)
  prepc_k<<<515, 256, 0, stream>>>(Wsrc1, WsT1, Wl1, WlT1, Wsrc2, WsT2, Wl2, WlT2,
                                   asrc1, Wdst1, adst1, asrc2, Wdst2, adst2,
                                   wa_s1, wa_d1, wa_s2, wa_d2);

  // layer 1
  gemm1_k<<<cdiv(N, 64), 256, 0, stream>>>(x, WsT1, WlT1, wa_s1, wa_d1,
                                           hbuf, linb, als1, ald1, N);
  ew_k<<<cdiv(E, 256), 256, 0, stream>>>(csrs, csrd, als1, ald1, ew, E);
  agg1_k<<<cdiv(N, 4), 256, 0, stream>>>(rowptr, csrs, ew, hbuf, linb, b1, bl1,
                                         wa_s2, wa_d2, x1b, als2, ald2, N);

  // layer 2
  gemm2_k<<<cdiv(N, 64), 256, 0, stream>>>(x1b, WsT2, WlT2, hbuf, linb, N);
  ew_k<<<cdiv(E, 256), 256, 0, stream>>>(csrs, csrd, als2, ald2, ew, E);

  // fused proj + agg2 + head
  tail_k<<<B, 512, 0, stream>>>(xproj, prjidx, W3, b3, pidx, rowptr, csrs, ew,
                                hbuf, linb, b2, bl2,
                                Wf1, bf1, Wf2, bf2, (float*)d_out, DPROJ);
}

// Round 12
// 177.673 us; speedup vs baseline: 1.1263x; 1.1263x over previous
//
#include <hip/hip_runtime.h>
#include <math.h>

#ifndef INFINITY
#define INFINITY __builtin_huge_valf()
#endif

static inline int cdiv(int a, int b){ return (a + b - 1) / b; }

typedef __attribute__((ext_vector_type(8))) short bf16x8;
typedef __attribute__((ext_vector_type(4))) float f32x4;
typedef __attribute__((ext_vector_type(4))) short short4v;

static __device__ __forceinline__ short f2bf(float f){
  unsigned u = __float_as_uint(f);
  unsigned r = (u + 0x7fffu + ((u >> 16) & 1u)) >> 16;
  return (short)r;
}
static __device__ __forceinline__ unsigned pk2bf(float lo, float hi){
  return ((unsigned)(unsigned short)f2bf(hi) << 16) | (unsigned short)(unsigned)f2bf(lo);
}
static __device__ __forceinline__ float bflo(unsigned pair){
  return __uint_as_float((pair & 0xffffu) << 16);
}
static __device__ __forceinline__ float bfhi(unsigned pair){
  return __uint_as_float(pair & 0xffff0000u);
}

// async global->LDS, 16B per lane, zero data VGPRs (m97 recipe)
#define GLOAD_LDS16(gsrc, ldst) \
  __builtin_amdgcn_global_load_lds((const __attribute__((address_space(1))) int*)(gsrc), \
                                   (__attribute__((address_space(3))) int*)(ldst), 16, 0, 0)

// ---------------- utility ----------------

__global__ void zero_i32_k(int* __restrict__ p, int n){
  int i = blockIdx.x * blockDim.x + threadIdx.x;
  if (i < n) p[i] = 0;
}

// fused weight prep: 4 transposes (blocks 0..511) + 4 combined attention vectors (blocks 512..514)
__global__ __launch_bounds__(256) void prepc_k(
    const float* __restrict__ Ws1, short* __restrict__ T1,
    const float* __restrict__ Wl1, short* __restrict__ T2,
    const float* __restrict__ Ws2, short* __restrict__ T3,
    const float* __restrict__ Wl2, short* __restrict__ T4,
    const float* __restrict__ as1, const float* __restrict__ Wd1, const float* __restrict__ ad1,
    const float* __restrict__ as2, const float* __restrict__ Wd2, const float* __restrict__ ad2,
    float* __restrict__ wa_s1, float* __restrict__ wa_d1,
    float* __restrict__ wa_s2, float* __restrict__ wa_d2){
  int g = blockIdx.x;
  if (g < 512){
    const float* W; short* T; int K; int c;
    if (g < 128){ W = Ws1; T = T1; K = 256; c = g; }
    else if (g < 256){ W = Wl1; T = T2; K = 256; c = g - 128; }
    else if (g < 384){ W = Ws2; T = T3; K = 128; c = g - 256; }
    else { W = Wl2; T = T4; K = 128; c = g - 384; }
    for (int k = threadIdx.x; k < K; k += blockDim.x)
      T[(size_t)c * K + k] = f2bf(W[(size_t)k * 128 + c]);
  } else {
    int t = (g - 512) * 256 + threadIdx.x;
    const float* row; const float* a; float* out; int idx;
    if (t < 256){ row = Ws1 + (size_t)t * 128;          a = as1; out = wa_s1; idx = t; }
    else if (t < 512){ row = Wd1 + (size_t)(t-256)*128; a = ad1; out = wa_d1; idx = t-256; }
    else if (t < 640){ row = Ws2 + (size_t)(t-512)*128; a = as2; out = wa_s2; idx = t-512; }
    else { row = Wd2 + (size_t)(t-640)*128;             a = ad2; out = wa_d2; idx = t-640; }
    float s = 0.f;
    #pragma unroll 8
    for (int j = 0; j < 128; ++j) s += row[j] * a[j];
    out[idx] = s;
  }
}

// ---------------- CSR build ----------------

__global__ void deg_count_k(const int* __restrict__ dst, int E, int* __restrict__ deg){
  int e = blockIdx.x * blockDim.x + threadIdx.x;
  if (e < E) atomicAdd(&deg[dst[e]], 1);
}

__global__ __launch_bounds__(1024) void scan1_k(const int* __restrict__ deg, int N,
    int* __restrict__ rowptr, int* __restrict__ bsum){
  __shared__ int buf[1024];
  int t = threadIdx.x;
  int i = blockIdx.x * 1024 + t;
  int v = (i < N) ? deg[i] : 0;
  buf[t] = v;
  __syncthreads();
  #pragma unroll
  for (int o = 1; o < 1024; o <<= 1){
    int add = (t >= o) ? buf[t - o] : 0;
    __syncthreads();
    buf[t] += add;
    __syncthreads();
  }
  if (i < N) rowptr[i] = buf[t] - v;
  if (t == 1023) bsum[blockIdx.x] = buf[1023];
}

__global__ __launch_bounds__(1024) void scan2_k(int* __restrict__ bsum, int nb,
    int* __restrict__ total_out){
  __shared__ int buf[1024];
  int t = threadIdx.x;
  int v = (t < nb) ? bsum[t] : 0;
  buf[t] = v;
  __syncthreads();
  #pragma unroll
  for (int o = 1; o < 1024; o <<= 1){
    int add = (t >= o) ? buf[t - o] : 0;
    __syncthreads();
    buf[t] += add;
    __syncthreads();
  }
  if (t < nb) bsum[t] = buf[t] - v;
  if (t == 1023) *total_out = buf[1023];
}

__global__ __launch_bounds__(1024) void scan3_k(int* __restrict__ rowptr, int* __restrict__ cursor,
    const int* __restrict__ boff, int N){
  int i = blockIdx.x * 1024 + threadIdx.x;
  if (i < N){
    int r = rowptr[i] + boff[blockIdx.x];
    rowptr[i] = r;
    cursor[i] = r;
  }
}

__global__ void scatter_k(const int* __restrict__ src, const int* __restrict__ dst, int E,
                          int* __restrict__ cursor, int* __restrict__ csrs, int* __restrict__ csrd){
  int e = blockIdx.x * blockDim.x + threadIdx.x;
  if (e < E){
    int d = dst[e];
    int p = atomicAdd(&cursor[d], 1);
    csrs[p] = src[e];
    csrd[p] = d;
  }
}

// per-CSR-slot softmax weight: ew[j] = exp(leaky_relu(als[src]+ald[dst]))
__global__ void ew_k(const int* __restrict__ csrs, const int* __restrict__ csrd,
                     const float* __restrict__ als, const float* __restrict__ ald,
                     float* __restrict__ ew, int E){
  int e = blockIdx.x * blockDim.x + threadIdx.x;
  if (e < E){
    float t = als[csrs[e]] + ald[csrd[e]];
    t = (t > 0.f) ? t : 0.2f * t;
    ew[e] = __expf(t);
  }
}

// ---------------- cast x->bf16 + fused layer-1 attention dots (pads rows to Mp with zeros) ----------------

__global__ __launch_bounds__(256) void cast_dots_k(const float* __restrict__ X, short* __restrict__ Xb,
    const float* __restrict__ vs, const float* __restrict__ vd,
    float* __restrict__ als, float* __restrict__ ald, int N, int Mp){
  int w = (blockIdx.x * blockDim.x + threadIdx.x) >> 6;
  int lane = threadIdx.x & 63;
  if (w >= Mp) return;
  int k = lane * 4;
  if (w < N){
    const float4 v = *(const float4*)(X + (size_t)w * 256 + k);
    float s = v.x * vs[k] + v.y * vs[k+1] + v.z * vs[k+2] + v.w * vs[k+3];
    float d = v.x * vd[k] + v.y * vd[k+1] + v.z * vd[k+2] + v.w * vd[k+3];
    #pragma unroll
    for (int o = 32; o; o >>= 1){ s += __shfl_xor(s, o); d += __shfl_xor(d, o); }
    short4v ob;
    ob.x = f2bf(v.x); ob.y = f2bf(v.y); ob.z = f2bf(v.z); ob.w = f2bf(v.w);
    *(short4v*)(Xb + (size_t)w * 256 + k) = ob;
    if (lane == 0){ als[w] = s; ald[w] = d; }
  } else {
    short4v z; z.x = 0; z.y = 0; z.z = 0; z.w = 0;
    *(short4v*)(Xb + (size_t)w * 256 + k) = z;
  }
}

// ---------------- m97-style GEMM: 64x128 tile, global_load_lds staging (0 data VGPRs), ----------------
// dual B, bf16 C, T21 swizzle (linear LDS dest + swizzled global src + swizzled ds_read).
// A [Mp][K] bf16 (padded), BT [128][K] bf16. C [Mp][128] bf16 unguarded.

template<int K, int NS>
__global__ __launch_bounds__(256) void gemm_gl_k(const short* __restrict__ A,
    const short* __restrict__ BT1, const short* __restrict__ BT2,
    short* __restrict__ C1, short* __restrict__ C2){
  __shared__ short As[64 * 32];     // 4 KB, 4 chunks of 1KB
  __shared__ short Bs1[128 * 32];   // 8 KB, 8 chunks
  __shared__ short Bs2[128 * 32];   // 8 KB, 8 chunks
  const int tid = threadIdx.x;
  const int lane = tid & 63, wid = tid >> 6;
  const int wm = wid >> 1, wn = wid & 1;
  const int l15 = lane & 15, lhi = lane >> 4;
  const int row0 = blockIdx.x * 64;
  // staging geometry: chunk = 16 rows x 32 cols; lane covers row chunk*16+(lane>>2),
  // LDS slot (lane&3); global col is the INVERSE-swizzled slot so that reads can swizzle.
  const int srow = lane >> 2;
  const int sslot = (lane & 3) ^ (srow & 3);   // slot^row&3 (involution)

  f32x4 acc[2][4], acc2[2][4];
  #pragma unroll
  for (int m = 0; m < 2; ++m)
    #pragma unroll
    for (int n = 0; n < 4; ++n){ acc[m][n] = (f32x4)(0.f); acc2[m][n] = (f32x4)(0.f); }

  for (int s = 0; s < NS; ++s){
    const int kk = s * 32;
    #pragma unroll
    for (int i = 0; i < 5; ++i){
      int g = wid * 5 + i;                       // 20 chunks: A 0-3, B1 4-11, B2 12-19
      const short* src; short* dst;
      if (g < 4){
        src = A + (size_t)(row0 + g * 16 + srow) * K + kk + sslot * 8;
        dst = As + g * 512;
      } else if (g < 12){
        int c = g - 4;
        src = BT1 + (size_t)(c * 16 + srow) * K + kk + sslot * 8;
        dst = Bs1 + c * 512;
      } else {
        int c = g - 12;
        src = BT2 + (size_t)(c * 16 + srow) * K + kk + sslot * 8;
        dst = Bs2 + c * 512;
      }
      GLOAD_LDS16(src, dst);
    }
    __syncthreads();                             // drains vmcnt(0): tiles ready
    bf16x8 af[2], b1f[4], b2f[4];
    #pragma unroll
    for (int m = 0; m < 2; ++m){
      int ar = wm * 32 + m * 16 + l15;
      af[m] = *(const bf16x8*)(As + ar * 32 + ((lhi ^ (ar & 3)) * 8));
    }
    #pragma unroll
    for (int n = 0; n < 4; ++n){
      int bc = wn * 64 + n * 16 + l15;
      int bo = bc * 32 + ((lhi ^ (bc & 3)) * 8);
      b1f[n] = *(const bf16x8*)(Bs1 + bo);
      b2f[n] = *(const bf16x8*)(Bs2 + bo);
    }
    #pragma unroll
    for (int m = 0; m < 2; ++m)
      #pragma unroll
      for (int n = 0; n < 4; ++n){
        acc[m][n]  = __builtin_amdgcn_mfma_f32_16x16x32_bf16(af[m], b1f[n], acc[m][n], 0, 0, 0);
        acc2[m][n] = __builtin_amdgcn_mfma_f32_16x16x32_bf16(af[m], b2f[n], acc2[m][n], 0, 0, 0);
      }
    __syncthreads();
  }
  #pragma unroll
  for (int m = 0; m < 2; ++m)
    #pragma unroll
    for (int n = 0; n < 4; ++n){
      int col = wn * 64 + n * 16 + l15;
      #pragma unroll
      for (int rr = 0; rr < 4; ++rr){
        int row = row0 + wm * 32 + m * 16 + lhi * 4 + rr;   // rows padded: unguarded
        C1[(size_t)row * 128 + col] = f2bf(acc[m][n][rr]);
        C2[(size_t)row * 128 + col] = f2bf(acc2[m][n][rr]);
      }
    }
}

// ---------------- layer-1 aggregation: precomputed edge weights, uniform loads, no shfl ----------------

__global__ __launch_bounds__(256) void agg1_k(const int* __restrict__ rowptr, const int* __restrict__ csrs,
    const float* __restrict__ ew,
    const short* __restrict__ hsrcb,
    const short* __restrict__ linb, const float* __restrict__ bg, const float* __restrict__ bl,
    const float* __restrict__ ws2, const float* __restrict__ wd2,
    short* __restrict__ outb, float* __restrict__ als2, float* __restrict__ ald2, int N){
  int w = (blockIdx.x * blockDim.x + threadIdx.x) >> 6;
  int lane = threadIdx.x & 63;
  if (w >= N) return;
  int beg = rowptr[w], end = rowptr[w + 1];
  float den = 0.f, a0 = 0.f, a1 = 0.f;
  int ch = lane << 1;
  for (int j0 = beg; j0 < end; j0 += 8){
    int sq[8]; float wq[8]; unsigned hp[8];
    #pragma unroll
    for (int u = 0; u < 8; ++u){
      int j = j0 + u;
      bool act = j < end;
      sq[u] = csrs[act ? j : beg];
      wq[u] = act ? ew[j] : 0.f;
    }
    #pragma unroll
    for (int u = 0; u < 8; ++u)
      hp[u] = *(const unsigned*)(hsrcb + (size_t)sq[u] * 128 + ch);
    #pragma unroll
    for (int u = 0; u < 8; ++u){
      den += wq[u];
      a0 += wq[u] * bflo(hp[u]); a1 += wq[u] * bfhi(hp[u]);
    }
  }
  float inv = (end > beg) ? 1.f / den : 0.f;
  unsigned lp = *(const unsigned*)(linb + (size_t)w * 128 + ch);
  float o0 = a0 * inv + bg[ch]     + bl[ch]     + bflo(lp);
  float o1 = a1 * inv + bg[ch + 1] + bl[ch + 1] + bfhi(lp);
  o0 = fmaxf(o0, 0.f); o1 = fmaxf(o1, 0.f);
  *(unsigned*)(outb + (size_t)w * 128 + ch) = pk2bf(o0, o1);
  float s2 = o0 * ws2[ch] + o1 * ws2[ch + 1];
  float d2 = o0 * wd2[ch] + o1 * wd2[ch + 1];
  #pragma unroll
  for (int o = 32; o; o >>= 1){ s2 += __shfl_xor(s2, o); d2 += __shfl_xor(d2, o); }
  if (lane == 0){ als2[w] = s2; ald2[w] = d2; }
}

// ---------------- fused tail: proj (fc3) + layer-2 aggregation (8 persons/block) + head ----------------

__global__ __launch_bounds__(512) void tail_k(
    const float* __restrict__ xp, const int* __restrict__ prjidx,
    const float* __restrict__ W3, const float* __restrict__ b3,
    const int* __restrict__ pidx,
    const int* __restrict__ rowptr, const int* __restrict__ csrs, const float* __restrict__ ew,
    const short* __restrict__ h2,
    const short* __restrict__ lin2all,
    const float* __restrict__ bg, const float* __restrict__ bl,
    const float* __restrict__ Wf1, const float* __restrict__ bf1,
    const float* __restrict__ Wf2, const float* __restrict__ bf2,
    float* __restrict__ outp, int Dp){
  __shared__ float xs[768];
  __shared__ float part[4][128];
  __shared__ float pe[8][128];
  __shared__ float pr[128];
  int b = blockIdx.x, t = threadIdx.x;
  // proj staging
  const float* xr = xp + (size_t)prjidx[b] * Dp;
  for (int i = t; i < Dp / 4; i += 512)
    ((float4*)xs)[i] = ((const float4*)xr)[i];
  __syncthreads();
  { int c = t & 127, h = t >> 7;
    float acc = 0.f;
    #pragma unroll 8
    for (int k = 0; k < 192; ++k)
      acc = fmaf(xs[h * 192 + k], W3[(size_t)(h * 192 + k) * 128 + c], acc);
    part[h][c] = acc; }
  // agg2: wave wv handles person b*8+wv
  int wv = t >> 6, lane = t & 63;
  int p = b * 8 + wv;
  int nd = pidx[p];
  int ch = lane << 1;
  int beg = rowptr[nd], end = rowptr[nd + 1];
  float den = 0.f, a0 = 0.f, a1 = 0.f;
  for (int j0 = beg; j0 < end; j0 += 8){
    int sq[8]; float wq[8]; unsigned hp[8];
    #pragma unroll
    for (int u = 0; u < 8; ++u){
      int j = j0 + u;
      bool act = j < end;
      sq[u] = csrs[act ? j : beg];
      wq[u] = act ? ew[j] : 0.f;
    }
    #pragma unroll
    for (int u = 0; u < 8; ++u)
      hp[u] = *(const unsigned*)(h2 + (size_t)sq[u] * 128 + ch);
    #pragma unroll
    for (int u = 0; u < 8; ++u){
      den += wq[u];
      a0 += wq[u] * bflo(hp[u]); a1 += wq[u] * bfhi(hp[u]);
    }
  }
  float inv = (end > beg) ? 1.f / den : 0.f;
  unsigned lp = *(const unsigned*)(lin2all + (size_t)nd * 128 + ch);
  pe[wv][ch]     = a0 * inv + bg[ch]     + bl[ch]     + bflo(lp);
  pe[wv][ch + 1] = a1 * inv + bg[ch + 1] + bl[ch + 1] + bfhi(lp);
  __syncthreads();
  if (t < 128) pr[t] = part[0][t] + part[1][t] + part[2][t] + part[3][t] + b3[t];
  __syncthreads();
  // head: wave wv -> person wv; lane covers cols lane, lane+64
  float v = 0.f;
  for (int cc = lane; cc < 128; cc += 64){
    float acc = bf1[cc];
    for (int k = 0; k < 128; ++k)
      acc += pe[wv][k] * Wf1[(size_t)k * 128 + cc] + pr[k] * Wf1[(size_t)(128 + k) * 128 + cc];
    v += fmaxf(acc, 0.f) * Wf2[cc];
  }
  #pragma unroll
  for (int o = 32; o; o >>= 1) v += __shfl_xor(v, o);
  if (lane == 0) outp[(size_t)b * 8 + wv] = v + bf2[0];
}

// ---------------- launch ----------------

extern "C" void kernel_launch(void* const* d_in, const int* in_sizes, int n_in,
                              void* d_out, int out_size, void* d_ws, size_t ws_size,
                              hipStream_t stream){
  const float* x      = (const float*)d_in[0];
  const int*   eidx   = (const int*)d_in[1];
  const float* xproj  = (const float*)d_in[2];
  const int*   pidx   = (const int*)d_in[3];
  const int*   prjidx = (const int*)d_in[4];
  const float* Wsrc1  = (const float*)d_in[5];
  const float* Wdst1  = (const float*)d_in[6];
  const float* asrc1  = (const float*)d_in[7];
  const float* adst1  = (const float*)d_in[8];
  const float* b1     = (const float*)d_in[9];
  const float* Wl1    = (const float*)d_in[10];
  const float* bl1    = (const float*)d_in[11];
  const float* Wsrc2  = (const float*)d_in[12];
  const float* Wdst2  = (const float*)d_in[13];
  const float* asrc2  = (const float*)d_in[14];
  const float* adst2  = (const float*)d_in[15];
  const float* b2     = (const float*)d_in[16];
  const float* Wl2    = (const float*)d_in[17];
  const float* bl2    = (const float*)d_in[18];
  const float* W3     = (const float*)d_in[19];
  const float* b3     = (const float*)d_in[20];
  const float* Wf1    = (const float*)d_in[21];
  const float* bf1    = (const float*)d_in[22];
  const float* Wf2    = (const float*)d_in[23];
  const float* bf2    = (const float*)d_in[24];

  const int DIN = 256, H = 128, DPROJ = 768;
  const int N  = in_sizes[0] / DIN;
  const int E  = in_sizes[1] / 2;
  const int P  = in_sizes[3];            // B*K = 2048
  const int B  = in_sizes[4];            // 256
  const int* srcv = eidx;
  const int* dstv = eidx + E;
  const int NB = cdiv(N, 1024);
  const int Mp = cdiv(N, 64) * 64;       // padded rows for unguarded GEMM staging/writes
  (void)H; (void)P;

  char* ws = (char*)d_ws;
  size_t off = 0;
  auto alloc = [&](size_t bytes) -> void* {
    void* p = ws + off;
    off = (off + bytes + 255) & ~(size_t)255;
    return p;
  };
  short* xb     = (short*)alloc((size_t)Mp * 256 * 2);  // bf16 x (padded)
  short* hbuf   = (short*)alloc((size_t)Mp * 128 * 2);  // bf16 h_src1, later h_src2
  short* linb   = (short*)alloc((size_t)Mp * 128 * 2);  // bf16 x@Wl1, later x1@Wl2
  short* x1b    = (short*)alloc((size_t)Mp * 128 * 2);  // bf16 x1
  float* als1   = (float*)alloc((size_t)N * 4);
  float* ald1   = (float*)alloc((size_t)N * 4);
  float* als2   = (float*)alloc((size_t)N * 4);
  float* ald2   = (float*)alloc((size_t)N * 4);
  float* wa_s1  = (float*)alloc(256 * 4);
  float* wa_d1  = (float*)alloc(256 * 4);
  float* wa_s2  = (float*)alloc(128 * 4);
  float* wa_d2  = (float*)alloc(128 * 4);
  short* WsT1   = (short*)alloc((size_t)128 * 256 * 2);
  short* WlT1   = (short*)alloc((size_t)128 * 256 * 2);
  short* WsT2   = (short*)alloc((size_t)128 * 128 * 2);
  short* WlT2   = (short*)alloc((size_t)128 * 128 * 2);
  int*   deg    = (int*)alloc((size_t)N * 4);
  int*   rowptr = (int*)alloc((size_t)(N + 1) * 4);
  int*   cursor = (int*)alloc((size_t)N * 4);
  int*   bsum   = (int*)alloc((size_t)1024 * 4);
  int*   csrs   = (int*)alloc((size_t)E * 4);
  int*   csrd   = (int*)alloc((size_t)E * 4);
  float* ew     = (float*)alloc((size_t)E * 4);
  (void)ws_size; (void)n_in; (void)out_size;

  // CSR build
  zero_i32_k<<<cdiv(N, 1024), 1024, 0, stream>>>(deg, N);
  deg_count_k<<<cdiv(E, 256), 256, 0, stream>>>(dstv, E, deg);
  scan1_k<<<NB, 1024, 0, stream>>>(deg, N, rowptr, bsum);
  scan2_k<<<1, 1024, 0, stream>>>(bsum, NB, rowptr + N);
  scan3_k<<<NB, 1024, 0, stream>>>(rowptr, cursor, bsum, N);
  scatter_k<<<cdiv(E, 256), 256, 0, stream>>>(srcv, dstv, E, cursor, csrs, csrd);

  // weight prep (transposes + combined attention vectors)
  prepc_k<<<515, 256, 0, stream>>>(Wsrc1, WsT1, Wl1, WlT1, Wsrc2, WsT2, Wl2, WlT2,
                                   asrc1, Wdst1, adst1, asrc2, Wdst2, adst2,
                                   wa_s1, wa_d1, wa_s2, wa_d2);

  // cast x -> bf16 (padded) + fused layer-1 dots
  cast_dots_k<<<cdiv(Mp, 4), 256, 0, stream>>>(x, xb, wa_s1, wa_d1, als1, ald1, N, Mp);

  // layer 1: h1 = x@Wsrc1, lin1 = x@Wl1 (gload_lds GEMM, dual)
  gemm_gl_k<256, 8><<<Mp / 64, 256, 0, stream>>>(xb, WsT1, WlT1, hbuf, linb);
  ew_k<<<cdiv(E, 256), 256, 0, stream>>>(csrs, csrd, als1, ald1, ew, E);
  agg1_k<<<cdiv(N, 4), 256, 0, stream>>>(rowptr, csrs, ew, hbuf, linb, b1, bl1,
                                         wa_s2, wa_d2, x1b, als2, ald2, N);

  // layer 2: h2 = x1@Wsrc2, lin2all = x1@Wl2 (dual)
  gemm_gl_k<128, 4><<<Mp / 64, 256, 0, stream>>>(x1b, WsT2, WlT2, hbuf, linb);
  ew_k<<<cdiv(E, 256), 256, 0, stream>>>(csrs, csrd, als2, ald2, ew, E);

  // fused proj + agg2 + head
  tail_k<<<B, 512, 0, stream>>>(xproj, prjidx, W3, b3, pidx, rowptr, csrs, ew,
                                hbuf, linb, b2, bl2,
                                Wf1, bf1, Wf2, bf2, (float*)d_out, DPROJ);
}